// Round 11
// baseline (195.485 us; speedup 1.0000x reference)
//
#include <hip/hip_runtime.h>

// Round 16 = r15 with the POISONED-PIPELINE fix + depth-3.
// r15's 845 cy/site despite a correct counted-lgkm pipeline: the x-quads
// were COMPILER ds_reads consumed inside the pipeline zone; SIInsertWaitcnts
// can't see through asm volatile, resets its counter model at each asm, and
// inserts its own s_waitcnt lgkmcnt(0) before every compiler-load use —
// draining the hand pipeline at every site. Fix: x-quads are ALSO loaded by
// inline-asm ds_read_b128, so the steady loop contains only asm DS ops and
// asm waits; the compiler has no loads of its own to wait on.
// Also deepened to 3 sites in flight (max 12 outstanding < lgkm cap 15):
// prologue issues x(8)+site0, wait(4) [x done], issue site1+site2; loop j:
// wait lgkmcnt(8) [site j ready, 2 sites in flight], sched_barrier (rule
// #18), issue site j+3, sched_barrier, compute site j. Tail waits 8/4/0.
// DS returns are in-order per wave -> counted waits are exact.
// Structure unchanged from r11/r15: E=1 bond/lane, K=2 batches packed in
// v2f (DS floor 288 cy/site/CU ~ VALU 288 cy), 2 waves/SIMD, CST=20
// scatter (0 measured bank conflicts), op_sel site_step (absmax 8.7e-19).

#define NSITES 784
#define DIM    8
#define ODIM   10
#define LABEL  392
#define WSITE  160   // floats per staged site: 8 columns * 20
#define CST    20    // column stride: col e at banks (20e mod 32)
#define XPST   34    // x pair-row stride: 16 sites * 2 + 2 pad

typedef float v2f __attribute__((ext_vector_type(2)));
typedef float v4f __attribute__((ext_vector_type(4)));

// quad_perm / row_half_mirror rotations (e = lane&7)
__device__ __forceinline__ float dpp_q1(float s){float d;asm("v_mov_b32_dpp %0, %1 quad_perm:[1,0,3,2] row_mask:0xf bank_mask:0xf":"=v"(d):"v"(s));return d;}
__device__ __forceinline__ float dpp_q2(float s){float d;asm("v_mov_b32_dpp %0, %1 quad_perm:[2,3,0,1] row_mask:0xf bank_mask:0xf":"=v"(d):"v"(s));return d;}
__device__ __forceinline__ float dpp_q3(float s){float d;asm("v_mov_b32_dpp %0, %1 quad_perm:[3,2,1,0] row_mask:0xf bank_mask:0xf":"=v"(d):"v"(s));return d;}
__device__ __forceinline__ float dpp_x7(float s){float d;asm("v_mov_b32_dpp %0, %1 row_half_mirror row_mask:0xf bank_mask:0xf":"=v"(d):"v"(s));return d;}

__device__ __forceinline__ v2f pk_fma(v2f a, v2f b, v2f c){v2f d;asm("v_pk_fma_f32 %0,%1,%2,%3":"=v"(d):"v"(a),"v"(b),"v"(c));return d;}
__device__ __forceinline__ v2f pk_sub(v2f a, v2f b){v2f d;asm("v_pk_add_f32 %0,%1,%2 neg_lo:[0,1] neg_hi:[0,1]":"=v"(d):"v"(a),"v"(b));return d;}
// src1 broadcast: both result halves read the SAME 32-bit half of src1
__device__ __forceinline__ v2f pk_mul_blo(v2f a, v2f b){v2f d;asm("v_pk_mul_f32 %0,%1,%2 op_sel:[0,0] op_sel_hi:[1,0]":"=v"(d):"v"(a),"v"(b));return d;}
__device__ __forceinline__ v2f pk_fma_blo(v2f a, v2f b, v2f c){v2f d;asm("v_pk_fma_f32 %0,%1,%2,%3 op_sel:[0,0,0] op_sel_hi:[1,0,1]":"=v"(d):"v"(a),"v"(b),"v"(c));return d;}
__device__ __forceinline__ v2f pk_fma_bhi(v2f a, v2f b, v2f c){v2f d;asm("v_pk_fma_f32 %0,%1,%2,%3 op_sel:[0,1,0] op_sel_hi:[1,1,1]":"=v"(d):"v"(a),"v"(b),"v"(c));return d;}

__device__ __forceinline__ v2f XY4(v4f q){ v2f r; r.x = q.x; r.y = q.y; return r; }
__device__ __forceinline__ v2f ZW4(v4f q){ v2f r; r.x = q.z; r.y = q.w; return r; }

// LDS byte address for inline-asm ds ops (generic LDS pointer: low 32 = offset)
__device__ __forceinline__ unsigned lds_off(const void* p) {
    return (unsigned)(unsigned long long)p;
}
// issue 4 ds_read_b128. "=&v": outputs must not alias the address input
// (r14's timing-sparse corruption; fixed and verified in r15).
__device__ __forceinline__ void ds_read4(unsigned a, v4f& r0, v4f& r1, v4f& r2, v4f& r3) {
    asm volatile("ds_read_b128 %0, %4 offset:0\n\t"
                 "ds_read_b128 %1, %4 offset:16\n\t"
                 "ds_read_b128 %2, %4 offset:32\n\t"
                 "ds_read_b128 %3, %4 offset:48"
                 : "=&v"(r0), "=&v"(r1), "=&v"(r2), "=&v"(r3) : "v"(a));
}

// One MPS site for 2 packed batches; lane owns output bond e. Weights in regs.
// r0/r1 = f0 m0..3 / m4..7 ; r2/r3 = f1. Verified r11/r15 (absmax 8.7e-19).
__device__ __forceinline__ v2f site_step(v2f v, v4f r0, v4f r1, v4f r2, v4f r3, v2f pp) {
    v2f t1; t1.x = dpp_q1(v.x);  t1.y = dpp_q1(v.y);   // v[e^1]
    v2f t2; t2.x = dpp_q2(v.x);  t2.y = dpp_q2(v.y);   // v[e^2]
    v2f t3; t3.x = dpp_q3(v.x);  t3.y = dpp_q3(v.y);   // v[e^3]
    v2f t7; t7.x = dpp_x7(v.x);  t7.y = dpp_x7(v.y);   // v[e^7]
    v2f t6; t6.x = dpp_q1(t7.x); t6.y = dpp_q1(t7.y);  // v[e^6]
    v2f t5; t5.x = dpp_q2(t7.x); t5.y = dpp_q2(t7.y);  // v[e^5]
    v2f t4; t4.x = dpp_q3(t7.x); t4.y = dpp_q3(t7.y);  // v[e^4]
    v2f a0 = pk_mul_blo(v,  XY4(r0));
    a0 = pk_fma_bhi(t1, XY4(r0), a0);
    a0 = pk_fma_blo(t2, ZW4(r0), a0);
    a0 = pk_fma_bhi(t3, ZW4(r0), a0);
    a0 = pk_fma_blo(t4, XY4(r1), a0);
    a0 = pk_fma_bhi(t5, XY4(r1), a0);
    a0 = pk_fma_blo(t6, ZW4(r1), a0);
    a0 = pk_fma_bhi(t7, ZW4(r1), a0);
    v2f a1 = pk_mul_blo(v,  XY4(r2));
    a1 = pk_fma_bhi(t1, XY4(r2), a1);
    a1 = pk_fma_blo(t2, ZW4(r2), a1);
    a1 = pk_fma_bhi(t3, ZW4(r2), a1);
    a1 = pk_fma_blo(t4, XY4(r3), a1);
    a1 = pk_fma_bhi(t5, XY4(r3), a1);
    a1 = pk_fma_blo(t6, ZW4(r3), a1);
    a1 = pk_fma_bhi(t7, ZW4(r3), a1);
    const v2f df = pk_sub(a1, a0);
    return pk_fma(pp, df, a0);                // (1-p)a0 + p a1 per packed batch
}

__global__ __launch_bounds__(256, 2) void mps_fused(
    const float* __restrict__ x,      // [B, N]
    const float* __restrict__ w0,     // [2, D]
    const float* __restrict__ Wl,     // [391, d, f, e]
    const float* __restrict__ wlab,   // [D, 2, D, O] = 1280 floats
    const float* __restrict__ Wr,     // [390, d, f, e]
    const float* __restrict__ wlast,  // [D, 2]
    float* __restrict__ out)          // [B, O]
{
    __shared__ float wb[2][2][16 * WSITE];  // [side][buf] 40.0 KB
    __shared__ float xb[2][2][16 * XPST];   // [side][buf]  8.5 KB
    __shared__ float wl[1280];              // 5.1 KB
    __shared__ float vout[2][256];          // 2.0 KB        (~55.6 KB total)

    const int tid  = threadIdx.x;
    const int side = tid >> 7;              // waves 0-1: left, 2-3: right
    const int stid = tid & 127;
    const int w    = stid >> 6;             // wave within side 0..1
    const int lane = stid & 63;
    const int e    = lane & 7;              // owned bond index
    const int g    = lane >> 3;             // batch group 0..7
    const int pr   = w * 8 + g;             // pair-row 0..15
    const int bl0  = w * 16 + g;            // lane's two block-local batches
    const int bl1  = w * 16 + 8 + g;
    const int b0   = blockIdx.x * 32;       // 32 batches per block, grid 512

    for (int k = tid; k < 320; k += 256)
        *(float4*)&wl[k * 4] = *(const float4*)&wlab[k * 4];

    // ------- staging registers (T14: load early, write late) -------
    float4 wr[4];
    float  xr[4];

    auto stage_load = [&](int c, int nt) {
        const float* W = side == 0 ? Wl : Wr;
        #pragma unroll
        for (int r = 0; r < 4; ++r) {
            const int cid = stid + 128 * r;        // 0..511 = 16 sites x 32
            const int s   = cid >> 5;
            const int u   = cid & 31;
            if (s < nt) {
                const int row = side == 0 ? (c * 16 + s) : (389 - c * 16 - s);
                wr[r] = *(const float4*)(W + (size_t)row * 128 + u * 4);
            }
        }
        #pragma unroll
        for (int r = 0; r < 4; ++r) {
            const int cid = stid + 128 * r;        // 0..511 = 32 b x 16 s
            const int b   = cid >> 4;
            const int sx  = cid & 15;
            if (sx < nt) {
                const int col = side == 0 ? (1 + c * 16 + sx) : (782 - c * 16 - sx);
                xr[r] = x[(size_t)(b0 + b) * NSITES + col];
            }
        }
    };

    // scatter (r11-verified, 0 bank conflicts):
    //   left  W[d][f][e] -> s*160 + e*20 + f*8 + (e^d)
    //   right W[d][f][e] -> s*160 + d*20 + f*8 + (d^e)
    auto stage_write = [&](int bufi, int nt) {
        float* wdst = wb[side][bufi];
        float* xdst = xb[side][bufi];
        #pragma unroll
        for (int r = 0; r < 4; ++r) {
            const int cid = stid + 128 * r;
            const int s   = cid >> 5;
            const int u   = cid & 31;
            const int d   = u >> 2;
            const int f   = (u >> 1) & 1;
            const int e4  = (u & 1) * 4;
            if (s < nt) {
                float* dst = wdst + s * WSITE + f * 8;
                const float vals[4] = {wr[r].x, wr[r].y, wr[r].z, wr[r].w};
                #pragma unroll
                for (int k = 0; k < 4; ++k) {
                    const int ee = e4 + k;
                    if (side == 0)
                        dst[ee * CST + (ee ^ d)] = vals[k];
                    else
                        dst[d * CST + (d ^ ee)] = vals[k];
                }
            }
        }
        #pragma unroll
        for (int r = 0; r < 4; ++r) {
            const int cid  = stid + 128 * r;
            const int b    = cid >> 4;
            const int sx   = cid & 15;
            const int prw  = (b >> 4) * 8 + (b & 7);
            const int half = (b >> 3) & 1;
            if (sx < nt)
                xdst[prw * XPST + sx * 2 + half] = xr[r];
        }
    };

    // ------- boundary init: v[e] for batches bl0, bl1 -------
    v2f vv;
    if (side == 0) {
        const float p0 = x[(size_t)(b0 + bl0) * NSITES];
        const float p1 = x[(size_t)(b0 + bl1) * NSITES];
        vv.x = fmaf(1.0f - p0, w0[e], p0 * w0[DIM + e]);
        vv.y = fmaf(1.0f - p1, w0[e], p1 * w0[DIM + e]);
    } else {
        const float p0 = x[(size_t)(b0 + bl0) * NSITES + (NSITES - 1)];
        const float p1 = x[(size_t)(b0 + bl1) * NSITES + (NSITES - 1)];
        vv.x = fmaf(1.0f - p0, wlast[e * 2], p0 * wlast[e * 2 + 1]);
        vv.y = fmaf(1.0f - p1, wlast[e * 2], p1 * wlast[e * 2 + 1]);
    }

    const int nt_tail = side ? 6 : 7;

    stage_load(0, 16);
    stage_write(0, 16);
    int buf = 0;

    // 16 sites; ALL-ASM depth-3 LDS pipeline. No compiler DS loads inside
    // the pipeline zone (x read via asm too), so SIInsertWaitcnts emits no
    // poisoning lgkmcnt(0). Max outstanding 12 < lgkm counter cap 15.
    auto compute16 = [&](int bufi) {
        const float* wp = &wb[side][bufi][e * CST];
        const float* xp = &xb[side][bufi][pr * XPST];
        const unsigned wbase = lds_off(wp);
        const unsigned xbase = lds_off(xp);
        v4f xq[8];
        v4f R[4][4];
        ds_read4(xbase,      xq[0], xq[1], xq[2], xq[3]);     // x: 8 reads
        ds_read4(xbase + 64, xq[4], xq[5], xq[6], xq[7]);
        ds_read4(wbase, R[0][0], R[0][1], R[0][2], R[0][3]);  // site 0
        asm volatile("s_waitcnt lgkmcnt(4)" ::: "memory");    // x done
        __builtin_amdgcn_sched_barrier(0);
        ds_read4(wbase + 1u * WSITE * 4, R[1][0], R[1][1], R[1][2], R[1][3]);
        ds_read4(wbase + 2u * WSITE * 4, R[2][0], R[2][1], R[2][2], R[2][3]);
        #pragma unroll
        for (int j = 0; j < 16; ++j) {
            if (j < 14)      asm volatile("s_waitcnt lgkmcnt(8)" ::: "memory");
            else if (j == 14) asm volatile("s_waitcnt lgkmcnt(4)" ::: "memory");
            else             asm volatile("s_waitcnt lgkmcnt(0)" ::: "memory");
            __builtin_amdgcn_sched_barrier(0);                // rule #18
            if (j < 13) {
                const int k = (j + 3) & 3;
                ds_read4(wbase + (unsigned)((j + 3) * WSITE * 4),
                         R[k][0], R[k][1], R[k][2], R[k][3]);
            }
            __builtin_amdgcn_sched_barrier(0);                // pin issue early
            const int m = j & 3;
            const v2f pp = (j & 1) ? ZW4(xq[j >> 1]) : XY4(xq[j >> 1]);
            vv = site_step(vv, R[m][0], R[m][1], R[m][2], R[m][3], pp);
        }
    };

    #pragma unroll 1
    for (int c = 0; c < 23; ++c) {            // chunks 0..22 (full)
        __syncthreads();                      // chunk c staged; buf^1 free
        stage_load(c + 1, 16);
        compute16(buf);
        __builtin_amdgcn_sched_barrier(0);    // keep LDS writes after compute
        stage_write(buf ^ 1, 16);
        buf ^= 1;
    }

    // chunk 23 (full) + prefetch tail chunk 24
    __syncthreads();
    stage_load(24, nt_tail);
    compute16(buf);
    __builtin_amdgcn_sched_barrier(0);
    stage_write(buf ^ 1, nt_tail);
    buf ^= 1;

    // tail chunk 24 (7 sites left / 6 sites right) — plain compiler loads
    __syncthreads();
    {
        const float* wp = &wb[side][buf][e * CST];
        const float* xp = &xb[side][buf][pr * XPST];
        for (int j = 0; j < nt_tail; ++j) {
            v4f r0 = *(const v4f*)(wp + j * WSITE + 0);
            v4f r1 = *(const v4f*)(wp + j * WSITE + 4);
            v4f r2 = *(const v4f*)(wp + j * WSITE + 8);
            v4f r3 = *(const v4f*)(wp + j * WSITE + 12);
            v2f pp; pp.x = xp[j * 2]; pp.y = xp[j * 2 + 1];
            vv = site_step(vv, r0, r1, r2, r3, pp);
        }
    }

    // ------- publish bond vectors and combine at the label site -------
    vout[side][bl0 * 8 + e] = vv.x;
    vout[side][bl1 * 8 + e] = vv.y;
    __syncthreads();

    for (int idx = tid; idx < 320; idx += 256) {   // 32 batches x 10 outputs
        const int b = idx / 10;
        const int o = idx - b * 10;
        const float p = x[(size_t)(b0 + b) * NSITES + LABEL];
        const float qq = 1.0f - p;
        const float* vl = &vout[0][b * 8];
        const float* rv = &vout[1][b * 8];
        float acc = 0.0f;
        #pragma unroll
        for (int d = 0; d < DIM; ++d) {
            const float vld = vl[d];
            #pragma unroll
            for (int ee = 0; ee < DIM; ++ee) {
                const float m = fmaf(qq, wl[((d * 2 + 0) * DIM + ee) * ODIM + o],
                                     p * wl[((d * 2 + 1) * DIM + ee) * ODIM + o]);
                acc = fmaf(vld * rv[ee], m, acc);
            }
        }
        out[(size_t)(b0 + b) * ODIM + o] = acc;
    }
}

extern "C" void kernel_launch(void* const* d_in, const int* in_sizes, int n_in,
                              void* d_out, int out_size, void* d_ws, size_t ws_size,
                              hipStream_t stream) {
    (void)in_sizes; (void)n_in; (void)d_ws; (void)ws_size; (void)out_size;
    const float* x     = (const float*)d_in[0];
    const float* w0    = (const float*)d_in[1];
    const float* Wl    = (const float*)d_in[2];
    const float* wlab  = (const float*)d_in[3];
    const float* Wr    = (const float*)d_in[4];
    const float* wlast = (const float*)d_in[5];

    mps_fused<<<512, 256, 0, stream>>>(x, w0, Wl, wlab, Wr, wlast, (float*)d_out);
}

// Round 12
// 158.887 us; speedup vs baseline: 1.2303x; 1.2303x over previous
//
#include <hip/hip_runtime.h>

// Round 17: r9 (best, 88 us) + conflict-free staging write order. NOTHING else.
// r16's decisive null: a provably-counted all-asm depth-3 LDS pipeline did not
// shorten the K=2 wall -> exposed ds_read latency was never the wall; all K=2
// restructures were attacking a phantom. The surviving model: r9 sits on the
// DS-pipe service ceiling (8 waves/CU x 8.25 b128/site x ~8cy ~ 528 ~ its 540
// cy/site), with one quantified overage: 3.59M bank-conflict cycles from the
// staging scatter (~35 cy/site of extra DS-pipe busy). This round removes it:
//  - left scatter: per store-instr all lanes shared float-parity (ee&1=k&1)
//    -> 64 lanes/16 banks (4-way). Fix: e4=4 lanes write pair-swapped order
//    (kk=k^1) -> opposite parity -> 32-bank tiling, 2-way (free).
//  - right scatter: bank=4(d>>1)+2(d^e) clusters (3-4-way pockets). Fix:
//    rotate write order by a=d>>1 (sg=(k+a)&3); enumeration shows exactly
//    2-way on all 32 banks. Values rotated via static ?: (rule #20 safe).
// Write POSITIONS unchanged -> numerics bit-identical to r9 (absmax 8.7e-19).

#define NSITES 784
#define DIM    8
#define ODIM   10
#define LABEL  392
#define WSITE  144   // floats per staged site: 4 q-columns * 36
#define QST    36    // column stride: 32 + 4 pad -> column q at banks 4q..4q+3
#define XST    20    // xb row stride: 16 sites + 4 pad

typedef float v2f __attribute__((ext_vector_type(2)));

// quad_perm rotations (each 4-lane quad = one batch's 4 output-pair lanes)
__device__ __forceinline__ float dpp_q1(float s){float d;asm("v_mov_b32_dpp %0, %1 quad_perm:[1,0,3,2] row_mask:0xf bank_mask:0xf":"=v"(d):"v"(s));return d;}
__device__ __forceinline__ float dpp_q2(float s){float d;asm("v_mov_b32_dpp %0, %1 quad_perm:[2,3,0,1] row_mask:0xf bank_mask:0xf":"=v"(d):"v"(s));return d;}
__device__ __forceinline__ float dpp_q3(float s){float d;asm("v_mov_b32_dpp %0, %1 quad_perm:[3,2,1,0] row_mask:0xf bank_mask:0xf":"=v"(d):"v"(s));return d;}

__device__ __forceinline__ v2f pk_mul(v2f a, v2f b){v2f d;asm("v_pk_mul_f32 %0,%1,%2":"=v"(d):"v"(a),"v"(b));return d;}
__device__ __forceinline__ v2f pk_fma(v2f a, v2f b, v2f c){v2f d;asm("v_pk_fma_f32 %0,%1,%2,%3":"=v"(d):"v"(a),"v"(b),"v"(c));return d;}
// src0 half-swapped: lo result uses src0.hi, hi result uses src0.lo
__device__ __forceinline__ v2f pk_fma_s(v2f a, v2f b, v2f c){v2f d;asm("v_pk_fma_f32 %0,%1,%2,%3 op_sel:[1,0,0] op_sel_hi:[0,1,1]":"=v"(d):"v"(a),"v"(b),"v"(c));return d;}
// src0 broadcast lo / broadcast hi (for the per-site p blend)
__device__ __forceinline__ v2f pk_fma_blo(v2f a, v2f b, v2f c){v2f d;asm("v_pk_fma_f32 %0,%1,%2,%3 op_sel:[0,0,0] op_sel_hi:[0,1,1]":"=v"(d):"v"(a),"v"(b),"v"(c));return d;}
__device__ __forceinline__ v2f pk_fma_bhi(v2f a, v2f b, v2f c){v2f d;asm("v_pk_fma_f32 %0,%1,%2,%3 op_sel:[1,0,0] op_sel_hi:[1,1,1]":"=v"(d):"v"(a),"v"(b),"v"(c));return d;}
// a - b
__device__ __forceinline__ v2f pk_sub(v2f a, v2f b){v2f d;asm("v_pk_add_f32 %0,%1,%2 neg_lo:[0,1] neg_hi:[0,1]":"=v"(d):"v"(a),"v"(b));return d;}

__device__ __forceinline__ v2f XY(const float4& q){ v2f r = {q.x, q.y}; return r; }
__device__ __forceinline__ v2f ZW(const float4& q){ v2f r = {q.z, q.w}; return r; }

// One MPS site for one batch, output pair (2q,2q+1) per lane.
// wc = lane's 32-float column: pair slot idx = f*8+m at floats idx*2..idx*2+1.
// Verified r9 (absmax 8.7e-19).
template <bool PHI>
__device__ __forceinline__ v2f site_step(v2f v, const float* wc, v2f pp) {
    const float4 r0 = *(const float4*)(wc + 0);    // f0 m0,m1
    const float4 r1 = *(const float4*)(wc + 4);    // f0 m2,m3
    const float4 r2 = *(const float4*)(wc + 8);    // f0 m4,m5
    const float4 r3 = *(const float4*)(wc + 12);   // f0 m6,m7
    const float4 r4 = *(const float4*)(wc + 16);   // f1 m0,m1
    const float4 r5 = *(const float4*)(wc + 20);   // f1 m2,m3
    const float4 r6 = *(const float4*)(wc + 24);   // f1 m4,m5
    const float4 r7 = *(const float4*)(wc + 28);   // f1 m6,m7
    v2f d1; d1.x = dpp_q1(v.x); d1.y = dpp_q1(v.y);   // v[·^2] pairs
    v2f d2; d2.x = dpp_q2(v.x); d2.y = dpp_q2(v.y);   // v[·^4] pairs
    v2f d3; d3.x = dpp_q3(v.x); d3.y = dpp_q3(v.y);   // v[·^6] pairs
    v2f a0 = pk_mul (v,  XY(r0));        // m0
    a0 = pk_fma_s(v,  ZW(r0), a0);       // m1 (swap)
    a0 = pk_fma  (d1, XY(r1), a0);       // m2
    a0 = pk_fma_s(d1, ZW(r1), a0);       // m3
    a0 = pk_fma  (d2, XY(r2), a0);       // m4
    a0 = pk_fma_s(d2, ZW(r2), a0);       // m5
    a0 = pk_fma  (d3, XY(r3), a0);       // m6
    a0 = pk_fma_s(d3, ZW(r3), a0);       // m7
    v2f a1 = pk_mul (v,  XY(r4));
    a1 = pk_fma_s(v,  ZW(r4), a1);
    a1 = pk_fma  (d1, XY(r5), a1);
    a1 = pk_fma_s(d1, ZW(r5), a1);
    a1 = pk_fma  (d2, XY(r6), a1);
    a1 = pk_fma_s(d2, ZW(r6), a1);
    a1 = pk_fma  (d3, XY(r7), a1);
    a1 = pk_fma_s(d3, ZW(r7), a1);
    const v2f df = pk_sub(a1, a0);
    return PHI ? pk_fma_bhi(pp, df, a0) : pk_fma_blo(pp, df, a0);
}

__global__ __launch_bounds__(256, 2) void mps_fused(
    const float* __restrict__ x,      // [B, N]
    const float* __restrict__ w0,     // [2, D]
    const float* __restrict__ Wl,     // [391, d, f, e]
    const float* __restrict__ wlab,   // [D, 2, D, O] = 1280 floats
    const float* __restrict__ Wr,     // [390, d, f, e]
    const float* __restrict__ wlast,  // [D, 2]
    float* __restrict__ out)          // [B, O]
{
    __shared__ float wb[2][2][16 * WSITE];  // [side][buf] 36.9 KB
    __shared__ float xb[2][2][32 * XST];    // [side][buf] 10.2 KB
    __shared__ float wl[1280];              // 5.1 KB
    __shared__ float vout[2][256];          // 2.0 KB          (~54 KB total)

    const int tid  = threadIdx.x;
    const int side = tid >> 7;              // waves 0-1: left, 2-3: right
    const int stid = tid & 127;
    const int w    = stid >> 6;             // wave within side 0..1
    const int lane = stid & 63;
    const int q    = lane & 3;              // output-pair index (e = 2q, 2q+1)
    const int grp  = lane >> 2;             // batch group 0..15
    const int bl   = w * 16 + grp;          // block-local batch 0..31
    const int b0   = blockIdx.x * 32;

    for (int k = tid; k < 320; k += 256)
        *(float4*)&wl[k * 4] = *(const float4*)&wlab[k * 4];

    // ------- staging registers (T14: load early, write late) -------
    float4 wr[4];
    float  xr[4];

    auto stage_load = [&](int c, int nt) {
        const float* W = side == 0 ? Wl : Wr;
        #pragma unroll
        for (int r = 0; r < 4; ++r) {
            const int cid = stid + 128 * r;        // 0..511 = 16 sites x 32
            const int s   = cid >> 5;
            const int u   = cid & 31;
            if (s < nt) {
                const int row = side == 0 ? (c * 16 + s) : (389 - c * 16 - s);
                wr[r] = *(const float4*)(W + (size_t)row * 128 + u * 4);
            }
        }
        #pragma unroll
        for (int r = 0; r < 4; ++r) {
            const int cid = stid + 128 * r;        // 0..511 = 32 b x 16 s
            const int b   = cid >> 4;
            const int sx  = cid & 15;
            if (sx < nt) {
                const int col = side == 0 ? (1 + c * 16 + sx) : (782 - c * 16 - sx);
                xr[r] = x[(size_t)(b0 + b) * NSITES + col];
            }
        }
    };

    // scatter positions identical to r9; only the WRITE ORDER differs:
    //  left : e4=4 lanes pair-swap (kk=k^1) -> per-instr banks cover both
    //         parities -> 2-way (was 4-way).
    //  right: rotate order by a=d>>1 (sg=(k+a)&3) -> per-instr banks are
    //         exactly 2-way across all 32 banks (was 3-4-way pockets).
    auto stage_write = [&](int bufi, int nt) {
        float* wdst = wb[side][bufi];
        float* xdst = xb[side][bufi];
        #pragma unroll
        for (int r = 0; r < 4; ++r) {
            const int cid = stid + 128 * r;
            const int s   = cid >> 5;
            const int u   = cid & 31;
            const int d   = u >> 2;
            const int f   = (u >> 1) & 1;
            const int hb  = u & 1;              // e4 selector (e4 = 4*hb)
            const int e4  = hb * 4;
            if (s < nt) {
                float* dst = wdst + s * WSITE;
                const float vals[4] = {wr[r].x, wr[r].y, wr[r].z, wr[r].w};
                if (side == 0) {
                    #pragma unroll
                    for (int k = 0; k < 4; ++k) {
                        const int kk = k ^ hb;                 // swapped order for e4=4
                        const int ee = e4 + kk;
                        const float va = hb ? vals[k ^ 1] : vals[k];
                        dst[(ee >> 1) * QST + (f * 8 + (ee ^ d)) * 2 + (ee & 1)] = va;
                    }
                } else {
                    const int a = d >> 1;
                    // rotated values: qk = vals[(k+a)&3], static selection
                    const float t0 = (a & 1) ? vals[1] : vals[0];
                    const float t1 = (a & 1) ? vals[2] : vals[1];
                    const float t2 = (a & 1) ? vals[3] : vals[2];
                    const float t3 = (a & 1) ? vals[0] : vals[3];
                    const float q0 = (a & 2) ? t2 : t0;
                    const float q1 = (a & 2) ? t3 : t1;
                    const float q2 = (a & 2) ? t0 : t2;
                    const float q3 = (a & 2) ? t1 : t3;
                    #pragma unroll
                    for (int k = 0; k < 4; ++k) {
                        const int sg = (k + a) & 3;
                        const int ee = e4 + sg;
                        const float va = (k == 0) ? q0 : (k == 1) ? q1 : (k == 2) ? q2 : q3;
                        dst[(d >> 1) * QST + (f * 8 + (d ^ ee)) * 2 + (d & 1)] = va;
                    }
                }
            }
        }
        #pragma unroll
        for (int r = 0; r < 4; ++r) {
            const int cid = stid + 128 * r;
            const int b   = cid >> 4;
            const int sx  = cid & 15;
            if (sx < nt)
                xdst[b * XST + sx] = xr[r];
        }
    };

    // ------- boundary init: output pair (2q, 2q+1) for batch bl -------
    v2f vv;
    {
        const int e0 = 2 * q, e1 = 2 * q + 1;
        if (side == 0) {
            const float p = x[(size_t)(b0 + bl) * NSITES];
            vv.x = fmaf(1.0f - p, w0[e0], p * w0[DIM + e0]);
            vv.y = fmaf(1.0f - p, w0[e1], p * w0[DIM + e1]);
        } else {
            const float p = x[(size_t)(b0 + bl) * NSITES + (NSITES - 1)];
            vv.x = fmaf(1.0f - p, wlast[e0 * 2], p * wlast[e0 * 2 + 1]);
            vv.y = fmaf(1.0f - p, wlast[e1 * 2], p * wlast[e1 * 2 + 1]);
        }
    }

    const int nt_tail = side ? 6 : 7;

    stage_load(0, 16);
    stage_write(0, 16);
    int buf = 0;

    auto compute16 = [&](int bufi) {
        const float* wp = &wb[side][bufi][q * QST];
        const float* xp = &xb[side][bufi][bl * XST];
        #pragma unroll
        for (int jb = 0; jb < 4; ++jb) {
            const float4 xq = *(const float4*)(xp + jb * 4);  // p for 4 sites
            const v2f p01 = XY(xq);
            const v2f p23 = ZW(xq);
            vv = site_step<false>(vv, wp + (jb * 4 + 0) * WSITE, p01);
            vv = site_step<true >(vv, wp + (jb * 4 + 1) * WSITE, p01);
            vv = site_step<false>(vv, wp + (jb * 4 + 2) * WSITE, p23);
            vv = site_step<true >(vv, wp + (jb * 4 + 3) * WSITE, p23);
        }
    };

    #pragma unroll 1
    for (int c = 0; c < 23; ++c) {            // chunks 0..22 (full)
        __syncthreads();                      // chunk c staged; buf^1 free
        stage_load(c + 1, 16);
        compute16(buf);
        __builtin_amdgcn_sched_barrier(0);    // keep LDS writes after compute
        stage_write(buf ^ 1, 16);
        buf ^= 1;
    }

    // chunk 23 (full) + prefetch tail chunk 24
    __syncthreads();
    stage_load(24, nt_tail);
    compute16(buf);
    __builtin_amdgcn_sched_barrier(0);
    stage_write(buf ^ 1, nt_tail);
    buf ^= 1;

    // tail chunk 24 (7 sites left / 6 sites right)
    __syncthreads();
    {
        const float* wp = &wb[side][buf][q * QST];
        const float* xp = &xb[side][buf][bl * XST];
        for (int j = 0; j < nt_tail; ++j) {
            v2f pp; pp.x = xp[j]; pp.y = pp.x;
            vv = site_step<false>(vv, wp + j * WSITE, pp);
        }
    }

    // ------- publish bond vectors and combine at the label site -------
    *(v2f*)&vout[side][bl * 8 + 2 * q] = vv;
    __syncthreads();

    for (int idx = tid; idx < 320; idx += 256) {   // 32 batches x 10 outputs
        const int b = idx / 10;
        const int o = idx - b * 10;
        const float p = x[(size_t)(b0 + b) * NSITES + LABEL];
        const float qq = 1.0f - p;
        const float* vl = &vout[0][b * 8];
        const float* rv = &vout[1][b * 8];
        float acc = 0.0f;
        #pragma unroll
        for (int d = 0; d < DIM; ++d) {
            const float vld = vl[d];
            #pragma unroll
            for (int ee = 0; ee < DIM; ++ee) {
                const float m = fmaf(qq, wl[((d * 2 + 0) * DIM + ee) * ODIM + o],
                                     p * wl[((d * 2 + 1) * DIM + ee) * ODIM + o]);
                acc = fmaf(vld * rv[ee], m, acc);
            }
        }
        out[(size_t)(b0 + b) * ODIM + o] = acc;
    }
}

extern "C" void kernel_launch(void* const* d_in, const int* in_sizes, int n_in,
                              void* d_out, int out_size, void* d_ws, size_t ws_size,
                              hipStream_t stream) {
    (void)in_sizes; (void)n_in; (void)d_ws; (void)ws_size; (void)out_size;
    const float* x     = (const float*)d_in[0];
    const float* w0    = (const float*)d_in[1];
    const float* Wl    = (const float*)d_in[2];
    const float* wlab  = (const float*)d_in[3];
    const float* Wr    = (const float*)d_in[4];
    const float* wlast = (const float*)d_in[5];

    mps_fused<<<512, 256, 0, stream>>>(x, w0, Wl, wlab, Wr, wlast, (float*)d_out);
}